// Round 1
// baseline (576.312 us; speedup 1.0000x reference)
//
#include <hip/hip_runtime.h>

#define NB 65536     // groups per batch
#define GPB 16       // groups per block (256 threads, 16 lanes/group)

__global__ __launch_bounds__(256) void agree_kernel(
    const int* __restrict__ group_inputs,
    const int* __restrict__ item_inputs,
    const int* __restrict__ group_members,
    const float* __restrict__ user_emb,
    const float* __restrict__ item_emb,
    const float* __restrict__ group_emb,
    const float* __restrict__ att_w1,
    const float* __restrict__ att_b1,
    const float* __restrict__ att_w2,
    const float* __restrict__ att_b2,
    const float* __restrict__ cls_w,
    const float* __restrict__ cls_b,
    const float* __restrict__ pred_w1,
    const float* __restrict__ pred_b1,
    const float* __restrict__ pred_w2,
    const float* __restrict__ pred_b2,
    float* __restrict__ out)
{
    // att_w1 [512][16]: 32 chunks of 16 rows, chunk stride 260 floats (16*16+4 pad)
    //   -> lane-t row-gather bank stride 260t ≡ 4t mod 32 = 2-way conflict (free)
    // pred_w1 [768][8]: 48 chunks of 16 rows, chunk stride 132 floats (16*8+4 pad)
    __shared__ __align__(16) float sW1[32 * 260];
    __shared__ __align__(16) float sWp[48 * 132];

    const int tid = threadIdx.x;

    // ---- stage weights to LDS (chunk-padded layout) ----
    {
        const float4* src = (const float4*)att_w1;       // 2048 float4
        for (int i = tid; i < 2048; i += 256) {
            float4 v = src[i];
            int r = i >> 2, cb = (i & 3) << 2;
            *(float4*)(sW1 + 260 * (r >> 4) + ((r & 15) << 4) + cb) = v;
        }
        const float4* srcp = (const float4*)pred_w1;     // 1536 float4
        for (int i = tid; i < 1536; i += 256) {
            float4 v = srcp[i];
            int r = i >> 1, cb = (i & 1) << 2;
            *(float4*)(sWp + 132 * (r >> 4) + ((r & 15) << 3) + cb) = v;
        }
    }
    __syncthreads();

    const int t = tid & 15;                 // lane within group (owns dims 16t..16t+15)
    const int b = blockIdx.x * GPB + (tid >> 4);

    const int g  = group_inputs[b];
    const int it = item_inputs[b];
    const int4 mem = ((const int4*)group_members)[g];

    // ---- gather member / item embeddings (register resident) ----
    float mbr[4][16];
    {
        const int mi[4] = {mem.x, mem.y, mem.z, mem.w};
        #pragma unroll
        for (int s = 0; s < 4; ++s) {
            const float4* p = (const float4*)user_emb + (((long)mi[s]) << 6) + (t << 2);
            #pragma unroll
            for (int k = 0; k < 4; ++k) {
                float4 v = p[k];
                mbr[s][4*k+0] = v.x; mbr[s][4*k+1] = v.y;
                mbr[s][4*k+2] = v.z; mbr[s][4*k+3] = v.w;
            }
        }
    }
    float itv[16];
    {
        const float4* p = (const float4*)item_emb + (((long)it) << 6) + (t << 2);
        #pragma unroll
        for (int k = 0; k < 4; ++k) {
            float4 v = p[k];
            itv[4*k+0] = v.x; itv[4*k+1] = v.y; itv[4*k+2] = v.z; itv[4*k+3] = v.w;
        }
    }

    // small uniform weights (compiler -> SGPR)
    float b1r[16], w2r[16];
    #pragma unroll
    for (int k = 0; k < 4; ++k) {
        float4 v = ((const float4*)att_b1)[k];
        b1r[4*k+0] = v.x; b1r[4*k+1] = v.y; b1r[4*k+2] = v.z; b1r[4*k+3] = v.w;
        float4 w = ((const float4*)att_w2)[k];
        w2r[4*k+0] = w.x; w2r[4*k+1] = w.y; w2r[4*k+2] = w.z; w2r[4*k+3] = w.w;
    }

    // ---- attention MLP: 2 passes of 8 hidden units ----
    float logit[4] = {0.f, 0.f, 0.f, 0.f};
    #pragma unroll
    for (int fh = 0; fh < 2; ++fh) {
        float acc[4][8], pi[8];
        #pragma unroll
        for (int f = 0; f < 8; ++f) {
            pi[f] = 0.f;
            #pragma unroll
            for (int s = 0; s < 4; ++s) acc[s][f] = 0.f;
        }
        #pragma unroll
        for (int j = 0; j < 16; ++j) {
            const float* wrA = sW1 + 260 * t + (j << 4) + (fh << 3);      // member rows
            float4 wa = *(const float4*)wrA;
            float4 wb = *(const float4*)(wrA + 4);
            const float* wrB = wrA + 260 * 16;                            // item rows (+256)
            float4 wc = *(const float4*)wrB;
            float4 wd = *(const float4*)(wrB + 4);
            #pragma unroll
            for (int s = 0; s < 4; ++s) {
                float mv = mbr[s][j];
                acc[s][0] += mv * wa.x; acc[s][1] += mv * wa.y;
                acc[s][2] += mv * wa.z; acc[s][3] += mv * wa.w;
                acc[s][4] += mv * wb.x; acc[s][5] += mv * wb.y;
                acc[s][6] += mv * wb.z; acc[s][7] += mv * wb.w;
            }
            float iv = itv[j];
            pi[0] += iv * wc.x; pi[1] += iv * wc.y; pi[2] += iv * wc.z; pi[3] += iv * wc.w;
            pi[4] += iv * wd.x; pi[5] += iv * wd.y; pi[6] += iv * wd.z; pi[7] += iv * wd.w;
        }
        // all-reduce partials across the 16 lanes of this group
        #pragma unroll
        for (int f = 0; f < 8; ++f) {
            #pragma unroll
            for (int s = 0; s < 4; ++s) {
                float v = acc[s][f];
                v += __shfl_xor(v, 1); v += __shfl_xor(v, 2);
                v += __shfl_xor(v, 4); v += __shfl_xor(v, 8);
                acc[s][f] = v;
            }
            float v = pi[f];
            v += __shfl_xor(v, 1); v += __shfl_xor(v, 2);
            v += __shfl_xor(v, 4); v += __shfl_xor(v, 8);
            pi[f] = v;
        }
        #pragma unroll
        for (int f = 0; f < 8; ++f) {
            float hb  = pi[f] + b1r[(fh << 3) + f];
            float w2v = w2r[(fh << 3) + f];
            #pragma unroll
            for (int s = 0; s < 4; ++s) {
                float h = acc[s][f] + hb;
                logit[s] += fmaxf(h, 0.f) * w2v;
            }
        }
    }

    // ---- softmax over 4 members (b2 cancels in softmax) ----
    float l0 = logit[0], l1 = logit[1], l2 = logit[2], l3 = logit[3];
    float mx = fmaxf(fmaxf(l0, l1), fmaxf(l2, l3));
    float e0 = __expf(l0 - mx), e1 = __expf(l1 - mx);
    float e2 = __expf(l2 - mx), e3 = __expf(l3 - mx);
    float den = e0 + e1 + e2 + e3;
    float at0 = e0 / den, at1 = e1 / den, at2 = e2 / den, at3 = e3 / den;

    // argmax (first-occurrence on ties, matches np.argmax)
    int best = 0; float bv = at0;
    if (at1 > bv) { bv = at1; best = 1; }
    if (at2 > bv) { bv = at2; best = 2; }
    if (at3 > bv) { bv = at3; best = 3; }

    // classifier: class of max-weight member
    float cw0 = cls_w[0], cw1 = cls_w[1], cb0 = cls_b[0], cb1 = cls_b[1];
    int pc = (bv * cw1 + cb1) > (bv * cw0 + cb0) ? 1 : 0;

    // ---- g_att: leader vs attention-weighted sum; g = g_att + group_emb ----
    float gvr[16];
    {
        const float4* p = (const float4*)group_emb + (((long)g) << 6) + (t << 2);
        #pragma unroll
        for (int k = 0; k < 4; ++k) {
            float4 v = p[k];
            gvr[4*k+0] = v.x; gvr[4*k+1] = v.y; gvr[4*k+2] = v.z; gvr[4*k+3] = v.w;
        }
    }
    float gvec[16], elv[16];
    #pragma unroll
    for (int d = 0; d < 16; ++d) {
        float w = at0 * mbr[0][d] + at1 * mbr[1][d] + at2 * mbr[2][d] + at3 * mbr[3][d];
        float ldr = mbr[0][d];
        ldr = (best == 1) ? mbr[1][d] : ldr;
        ldr = (best == 2) ? mbr[2][d] : ldr;
        ldr = (best == 3) ? mbr[3][d] : ldr;
        float ga = pc ? ldr : w;
        float gg = ga + gvr[d];
        gvec[d] = gg;
        elv[d]  = gg * itv[d];
    }

    // ---- prediction MLP: new = [elem, g, items] (3*256) -> 8 -> 1 ----
    float po[8] = {0.f,0.f,0.f,0.f,0.f,0.f,0.f,0.f};
    #pragma unroll
    for (int j = 0; j < 16; ++j) {
        const float* pA = sWp + 132 * t + (j << 3);          // elem rows
        float4 a0 = *(const float4*)pA, a1 = *(const float4*)(pA + 4);
        const float* pB = pA + 132 * 16;                     // g rows (+256)
        float4 g0 = *(const float4*)pB, g1 = *(const float4*)(pB + 4);
        const float* pC = pA + 132 * 32;                     // item rows (+512)
        float4 c0 = *(const float4*)pC, c1 = *(const float4*)(pC + 4);
        float e = elv[j], gg = gvec[j], iv = itv[j];
        po[0] += e * a0.x; po[0] += gg * g0.x; po[0] += iv * c0.x;
        po[1] += e * a0.y; po[1] += gg * g0.y; po[1] += iv * c0.y;
        po[2] += e * a0.z; po[2] += gg * g0.z; po[2] += iv * c0.z;
        po[3] += e * a0.w; po[3] += gg * g0.w; po[3] += iv * c0.w;
        po[4] += e * a1.x; po[4] += gg * g1.x; po[4] += iv * c1.x;
        po[5] += e * a1.y; po[5] += gg * g1.y; po[5] += iv * c1.y;
        po[6] += e * a1.z; po[6] += gg * g1.z; po[6] += iv * c1.z;
        po[7] += e * a1.w; po[7] += gg * g1.w; po[7] += iv * c1.w;
    }
    #pragma unroll
    for (int o = 0; o < 8; ++o) {
        float v = po[o];
        v += __shfl_xor(v, 1); v += __shfl_xor(v, 2);
        v += __shfl_xor(v, 4); v += __shfl_xor(v, 8);
        po[o] = v;
    }
    float pb1r[8], pw2r[8];
    #pragma unroll
    for (int k = 0; k < 2; ++k) {
        float4 v = ((const float4*)pred_b1)[k];
        pb1r[4*k+0] = v.x; pb1r[4*k+1] = v.y; pb1r[4*k+2] = v.z; pb1r[4*k+3] = v.w;
        float4 w = ((const float4*)pred_w2)[k];
        pw2r[4*k+0] = w.x; pw2r[4*k+1] = w.y; pw2r[4*k+2] = w.z; pw2r[4*k+3] = w.w;
    }
    float z = pred_b2[0];
    #pragma unroll
    for (int o = 0; o < 8; ++o)
        z += fmaxf(po[o] + pb1r[o], 0.f) * pw2r[o];
    float y = 1.f / (1.f + __expf(-z));

    // ---- outputs: y[NB] | at_wt[NB*4] | pred_class[NB] ----
    if (t == 0) {
        out[b] = y;
        *(float4*)(out + NB + 4 * b) = make_float4(at0, at1, at2, at3);
        out[5 * NB + b] = (float)pc;
    }
}

extern "C" void kernel_launch(void* const* d_in, const int* in_sizes, int n_in,
                              void* d_out, int out_size, void* d_ws, size_t ws_size,
                              hipStream_t stream) {
    (void)in_sizes; (void)n_in; (void)out_size; (void)d_ws; (void)ws_size;
    agree_kernel<<<NB / GPB, 256, 0, stream>>>(
        (const int*)d_in[0], (const int*)d_in[1], (const int*)d_in[2],
        (const float*)d_in[3], (const float*)d_in[4], (const float*)d_in[5],
        (const float*)d_in[6], (const float*)d_in[7], (const float*)d_in[8],
        (const float*)d_in[9], (const float*)d_in[10], (const float*)d_in[11],
        (const float*)d_in[12], (const float*)d_in[13], (const float*)d_in[14],
        (const float*)d_in[15], (float*)d_out);
}

// Round 2
// 555.209 us; speedup vs baseline: 1.0380x; 1.0380x over previous
//
#include <hip/hip_runtime.h>

#define NB 65536     // groups per batch
#define GPB 8        // groups per block (256 threads, 32 lanes/group)

// reduce-scatter an 8-vector over 32 lanes; returns full sum of feature
// f* = 4*b0 + 2*b1 + b2 (bits of lane t). Lanes t, t^8, t^16, t^24 duplicate.
__device__ __forceinline__ float rs8(const float v[8], int t) {
    const int b0 = t & 1, b1 = (t >> 1) & 1, b2 = (t >> 2) & 1;
    float w[4];
    #pragma unroll
    for (int i = 0; i < 4; ++i) {
        float send = b0 ? v[i] : v[i + 4];
        float recv = __shfl_xor(send, 1);
        w[i] = (b0 ? v[i + 4] : v[i]) + recv;
    }
    float x[2];
    #pragma unroll
    for (int i = 0; i < 2; ++i) {
        float send = b1 ? w[i] : w[i + 2];
        float recv = __shfl_xor(send, 2);
        x[i] = (b1 ? w[i + 2] : w[i]) + recv;
    }
    float send = b2 ? x[0] : x[1];
    float recv = __shfl_xor(send, 4);
    float u = (b2 ? x[1] : x[0]) + recv;
    u += __shfl_xor(u, 8);
    u += __shfl_xor(u, 16);
    return u;
}

__global__ __launch_bounds__(256, 4) void agree_kernel(
    const int* __restrict__ group_inputs,
    const int* __restrict__ item_inputs,
    const int* __restrict__ group_members,
    const float* __restrict__ user_emb,
    const float* __restrict__ item_emb,
    const float* __restrict__ group_emb,
    const float* __restrict__ att_w1,
    const float* __restrict__ att_b1,
    const float* __restrict__ att_w2,
    const float* __restrict__ att_b2,
    const float* __restrict__ cls_w,
    const float* __restrict__ cls_b,
    const float* __restrict__ pred_w1,
    const float* __restrict__ pred_b1,
    const float* __restrict__ pred_w2,
    const float* __restrict__ pred_b2,
    float* __restrict__ out)
{
    // Phase-split LDS union (33280 B -> 4 blocks/CU):
    //   phase A: att_w1 [512][16] as 32 chunks of 16 rows, chunk stride 260
    //   phase B: pred_w1 [768][8] as 48 chunks of 16 rows, chunk stride 132
    // lane-t row-gather bank stride == 2-way conflict (free) in both layouts.
    __shared__ __align__(16) float sBuf[32 * 260];

    const int tid = threadIdx.x;
    const int t = tid & 31;                 // lane within group (owns dims 8t..8t+7)
    const int b = blockIdx.x * GPB + (tid >> 5);

    // ---- issue gathers early (latency hides under weight staging) ----
    const int g  = group_inputs[b];
    const int it = item_inputs[b];
    const int4 mem = ((const int4*)group_members)[g];

    float mbr[4][8];
    {
        const int mi[4] = {mem.x, mem.y, mem.z, mem.w};
        #pragma unroll
        for (int s = 0; s < 4; ++s) {
            const float4* p = (const float4*)user_emb + (((long)mi[s]) << 6) + (t << 1);
            float4 v0 = p[0], v1 = p[1];
            mbr[s][0] = v0.x; mbr[s][1] = v0.y; mbr[s][2] = v0.z; mbr[s][3] = v0.w;
            mbr[s][4] = v1.x; mbr[s][5] = v1.y; mbr[s][6] = v1.z; mbr[s][7] = v1.w;
        }
    }
    float itv[8];
    {
        const float4* p = (const float4*)item_emb + (((long)it) << 6) + (t << 1);
        float4 v0 = p[0], v1 = p[1];
        itv[0] = v0.x; itv[1] = v0.y; itv[2] = v0.z; itv[3] = v0.w;
        itv[4] = v1.x; itv[5] = v1.y; itv[6] = v1.z; itv[7] = v1.w;
    }

    // per-lane feature id for the reduce-scatter output
    const int fstar = ((t & 1) << 2) + (t & 2) + ((t >> 2) & 1);
    const float ab1_0 = att_b1[fstar],     ab1_1 = att_b1[8 + fstar];
    const float aw2_0 = att_w2[fstar],     aw2_1 = att_w2[8 + fstar];
    const float pb1v  = pred_b1[fstar],    pw2v  = pred_w2[fstar];
    const float pb2v  = pred_b2[0];
    const float cw0 = cls_w[0], cw1 = cls_w[1], cb0 = cls_b[0], cb1 = cls_b[1];

    // ---- phase A: stage att_w1 ----
    {
        const float4* src = (const float4*)att_w1;       // 2048 float4
        for (int i = tid; i < 2048; i += 256) {
            float4 v = src[i];
            int r = i >> 2, cb = (i & 3) << 2;
            *(float4*)(sBuf + 260 * (r >> 4) + ((r & 15) << 4) + cb) = v;
        }
    }
    __syncthreads();

    // ---- attention MLP: 2 passes of 8 hidden units ----
    const float* mbase = sBuf + 260 * (t >> 1) + ((t & 1) << 7);  // member rows 8t..8t+7
    const float* ibase = mbase + 260 * 16;                        // item rows (+256)
    float logit[4] = {0.f, 0.f, 0.f, 0.f};
    #pragma unroll
    for (int fh = 0; fh < 2; ++fh) {
        float acc[4][8], pi[8];
        #pragma unroll
        for (int f = 0; f < 8; ++f) {
            pi[f] = 0.f;
            #pragma unroll
            for (int s = 0; s < 4; ++s) acc[s][f] = 0.f;
        }
        const float* mb = mbase + (fh << 3);
        const float* ib = ibase + (fh << 3);
        #pragma unroll
        for (int j = 0; j < 8; ++j) {
            float4 wa = *(const float4*)(mb + (j << 4));
            float4 wb = *(const float4*)(mb + (j << 4) + 4);
            float4 wc = *(const float4*)(ib + (j << 4));
            float4 wd = *(const float4*)(ib + (j << 4) + 4);
            #pragma unroll
            for (int s = 0; s < 4; ++s) {
                float mv = mbr[s][j];
                acc[s][0] += mv * wa.x; acc[s][1] += mv * wa.y;
                acc[s][2] += mv * wa.z; acc[s][3] += mv * wa.w;
                acc[s][4] += mv * wb.x; acc[s][5] += mv * wb.y;
                acc[s][6] += mv * wb.z; acc[s][7] += mv * wb.w;
            }
            float iv = itv[j];
            pi[0] += iv * wc.x; pi[1] += iv * wc.y; pi[2] += iv * wc.z; pi[3] += iv * wc.w;
            pi[4] += iv * wd.x; pi[5] += iv * wd.y; pi[6] += iv * wd.z; pi[7] += iv * wd.w;
        }
        float piR = rs8(pi, t);
        float hb  = piR + (fh ? ab1_1 : ab1_0);
        float w2v = fh ? aw2_1 : aw2_0;
        #pragma unroll
        for (int s = 0; s < 4; ++s) {
            float h = rs8(acc[s], t) + hb;
            logit[s] += fmaxf(h, 0.f) * w2v;
        }
    }
    // octet all-reduce: each lane's partial is its feature's contribution
    #pragma unroll
    for (int s = 0; s < 4; ++s) {
        float v = logit[s];
        v += __shfl_xor(v, 1); v += __shfl_xor(v, 2); v += __shfl_xor(v, 4);
        logit[s] = v;
    }

    // ---- softmax over 4 members (b2 cancels) ----
    float l0 = logit[0], l1 = logit[1], l2 = logit[2], l3 = logit[3];
    float mx = fmaxf(fmaxf(l0, l1), fmaxf(l2, l3));
    float e0 = __expf(l0 - mx), e1 = __expf(l1 - mx);
    float e2 = __expf(l2 - mx), e3 = __expf(l3 - mx);
    float den = e0 + e1 + e2 + e3;
    float at0 = e0 / den, at1 = e1 / den, at2 = e2 / den, at3 = e3 / den;

    int best = 0; float bv = at0;
    if (at1 > bv) { bv = at1; best = 1; }
    if (at2 > bv) { bv = at2; best = 2; }
    if (at3 > bv) { bv = at3; best = 3; }
    int pc = (bv * cw1 + cb1) > (bv * cw0 + cb0) ? 1 : 0;

    // group embedding gather (latency hides under phase-B staging)
    float gvr[8];
    {
        const float4* p = (const float4*)group_emb + (((long)g) << 6) + (t << 1);
        float4 v0 = p[0], v1 = p[1];
        gvr[0] = v0.x; gvr[1] = v0.y; gvr[2] = v0.z; gvr[3] = v0.w;
        gvr[4] = v1.x; gvr[5] = v1.y; gvr[6] = v1.z; gvr[7] = v1.w;
    }

    // ---- phase B: stage pred_w1 (overwrites sBuf) ----
    __syncthreads();
    {
        const float4* srcp = (const float4*)pred_w1;     // 1536 float4
        for (int i = tid; i < 1536; i += 256) {
            float4 v = srcp[i];
            int r = i >> 1, cb = (i & 1) << 2;
            *(float4*)(sBuf + 132 * (r >> 4) + ((r & 15) << 3) + cb) = v;
        }
    }

    // g_att while staging is in flight
    float gvec[8], elv[8];
    #pragma unroll
    for (int d = 0; d < 8; ++d) {
        float w = at0 * mbr[0][d] + at1 * mbr[1][d] + at2 * mbr[2][d] + at3 * mbr[3][d];
        float ldr = mbr[0][d];
        ldr = (best == 1) ? mbr[1][d] : ldr;
        ldr = (best == 2) ? mbr[2][d] : ldr;
        ldr = (best == 3) ? mbr[3][d] : ldr;
        float ga = pc ? ldr : w;
        float gg = ga + gvr[d];
        gvec[d] = gg;
        elv[d]  = gg * itv[d];
    }
    __syncthreads();

    // ---- prediction MLP: [elem, g, items] (3*256) -> 8 -> 1 ----
    const float* pbase = sBuf + 132 * (t >> 1) + ((t & 1) << 6);
    float po[8] = {0.f,0.f,0.f,0.f,0.f,0.f,0.f,0.f};
    #pragma unroll
    for (int j = 0; j < 8; ++j) {
        const float* pA = pbase + (j << 3);
        float4 a0 = *(const float4*)pA,          a1 = *(const float4*)(pA + 4);
        float4 g0 = *(const float4*)(pA + 2112), g1 = *(const float4*)(pA + 2116);
        float4 c0 = *(const float4*)(pA + 4224), c1 = *(const float4*)(pA + 4228);
        float e = elv[j], gg = gvec[j], iv = itv[j];
        po[0] += e * a0.x; po[0] += gg * g0.x; po[0] += iv * c0.x;
        po[1] += e * a0.y; po[1] += gg * g0.y; po[1] += iv * c0.y;
        po[2] += e * a0.z; po[2] += gg * g0.z; po[2] += iv * c0.z;
        po[3] += e * a0.w; po[3] += gg * g0.w; po[3] += iv * c0.w;
        po[4] += e * a1.x; po[4] += gg * g1.x; po[4] += iv * c1.x;
        po[5] += e * a1.y; po[5] += gg * g1.y; po[5] += iv * c1.y;
        po[6] += e * a1.z; po[6] += gg * g1.z; po[6] += iv * c1.z;
        po[7] += e * a1.w; po[7] += gg * g1.w; po[7] += iv * c1.w;
    }
    float poR = rs8(po, t);
    float z = fmaxf(poR + pb1v, 0.f) * pw2v;
    z += __shfl_xor(z, 1); z += __shfl_xor(z, 2); z += __shfl_xor(z, 4);
    z += pb2v;
    float y = 1.f / (1.f + __expf(-z));

    // ---- outputs: y[NB] | at_wt[NB*4] | pred_class[NB] ----
    if (t == 0) {
        out[b] = y;
        *(float4*)(out + NB + 4 * b) = make_float4(at0, at1, at2, at3);
        out[5 * NB + b] = (float)pc;
    }
}

extern "C" void kernel_launch(void* const* d_in, const int* in_sizes, int n_in,
                              void* d_out, int out_size, void* d_ws, size_t ws_size,
                              hipStream_t stream) {
    (void)in_sizes; (void)n_in; (void)out_size; (void)d_ws; (void)ws_size;
    agree_kernel<<<NB / GPB, 256, 0, stream>>>(
        (const int*)d_in[0], (const int*)d_in[1], (const int*)d_in[2],
        (const float*)d_in[3], (const float*)d_in[4], (const float*)d_in[5],
        (const float*)d_in[6], (const float*)d_in[7], (const float*)d_in[8],
        (const float*)d_in[9], (const float*)d_in[10], (const float*)d_in[11],
        (const float*)d_in[12], (const float*)d_in[13], (const float*)d_in[14],
        (const float*)d_in[15], (float*)d_out);
}

// Round 3
// 526.482 us; speedup vs baseline: 1.0946x; 1.0546x over previous
//
#include <hip/hip_runtime.h>

#define NB 65536     // groups per batch
#define GPB 8        // groups per block (256 threads, 32 lanes/group)

// Reduce-scatter an 8-vector over 32 lanes, ALL BY VALUE (no array pointer ->
// no alloca -> no scratch). Returns full sum of feature f* = 4*b0+2*b1+b2.
__device__ __forceinline__ float rs8v(float v0, float v1, float v2, float v3,
                                      float v4, float v5, float v6, float v7,
                                      bool b0, bool b1, bool b2) {
    float s, r;
    s = b0 ? v0 : v4; r = __shfl_xor(s, 1); float w0 = (b0 ? v4 : v0) + r;
    s = b0 ? v1 : v5; r = __shfl_xor(s, 1); float w1 = (b0 ? v5 : v1) + r;
    s = b0 ? v2 : v6; r = __shfl_xor(s, 1); float w2 = (b0 ? v6 : v2) + r;
    s = b0 ? v3 : v7; r = __shfl_xor(s, 1); float w3 = (b0 ? v7 : v3) + r;
    s = b1 ? w0 : w2; r = __shfl_xor(s, 2); float x0 = (b1 ? w2 : w0) + r;
    s = b1 ? w1 : w3; r = __shfl_xor(s, 2); float x1 = (b1 ? w3 : w1) + r;
    s = b2 ? x0 : x1; r = __shfl_xor(s, 4); float u = (b2 ? x1 : x0) + r;
    u += __shfl_xor(u, 8);
    u += __shfl_xor(u, 16);
    return u;
}

__global__ __launch_bounds__(256, 4) void agree_kernel(
    const int* __restrict__ group_inputs,
    const int* __restrict__ item_inputs,
    const int* __restrict__ group_members,
    const float* __restrict__ user_emb,
    const float* __restrict__ item_emb,
    const float* __restrict__ group_emb,
    const float* __restrict__ att_w1,
    const float* __restrict__ att_b1,
    const float* __restrict__ att_w2,
    const float* __restrict__ att_b2,
    const float* __restrict__ cls_w,
    const float* __restrict__ cls_b,
    const float* __restrict__ pred_w1,
    const float* __restrict__ pred_b1,
    const float* __restrict__ pred_w2,
    const float* __restrict__ pred_b2,
    float* __restrict__ out)
{
    // Phase-split LDS union (33280 B -> 4 blocks/CU):
    //   phase A: att_w1 [512][16] as 32 chunks of 16 rows, chunk stride 260
    //   phase B: pred_w1 [768][8] as 48 chunks of 16 rows, chunk stride 132
    __shared__ __align__(16) float sBuf[32 * 260];

    const int tid = threadIdx.x;
    const int t = tid & 31;                 // lane within group (owns dims 8t..8t+7)
    const int b = blockIdx.x * GPB + (tid >> 5);

    // ---- issue gathers early (latency hides under weight staging) ----
    const int g  = group_inputs[b];
    const int it = item_inputs[b];
    const int4 mem = ((const int4*)group_members)[g];

    float mbr[4][8];
    {
        const int mi[4] = {mem.x, mem.y, mem.z, mem.w};
        #pragma unroll
        for (int s = 0; s < 4; ++s) {
            const float4* p = (const float4*)user_emb + (((long)mi[s]) << 6) + (t << 1);
            float4 v0 = p[0], v1 = p[1];
            mbr[s][0] = v0.x; mbr[s][1] = v0.y; mbr[s][2] = v0.z; mbr[s][3] = v0.w;
            mbr[s][4] = v1.x; mbr[s][5] = v1.y; mbr[s][6] = v1.z; mbr[s][7] = v1.w;
        }
    }
    float itv[8];
    {
        const float4* p = (const float4*)item_emb + (((long)it) << 6) + (t << 1);
        float4 v0 = p[0], v1 = p[1];
        itv[0] = v0.x; itv[1] = v0.y; itv[2] = v0.z; itv[3] = v0.w;
        itv[4] = v1.x; itv[5] = v1.y; itv[6] = v1.z; itv[7] = v1.w;
    }

    const bool b0 = (t & 1), b1 = (t & 2), b2 = (t & 4);
    // per-lane feature id for the reduce-scatter output
    const int fstar = ((t & 1) << 2) + (t & 2) + ((t >> 2) & 1);
    const float ab1_0 = att_b1[fstar],     ab1_1 = att_b1[8 + fstar];
    const float aw2_0 = att_w2[fstar],     aw2_1 = att_w2[8 + fstar];
    const float pb1v  = pred_b1[fstar],    pw2v  = pred_w2[fstar];
    const float pb2v  = pred_b2[0];
    const float cw0 = cls_w[0], cw1 = cls_w[1], cb0 = cls_b[0], cb1 = cls_b[1];

    // ---- phase A: stage att_w1 ----
    {
        const float4* src = (const float4*)att_w1;       // 2048 float4
        for (int i = tid; i < 2048; i += 256) {
            float4 v = src[i];
            int r = i >> 2, cb = (i & 3) << 2;
            *(float4*)(sBuf + 260 * (r >> 4) + ((r & 15) << 4) + cb) = v;
        }
    }
    __syncthreads();

    // ---- attention MLP: 2 passes of 8 hidden units ----
    const float* mbase = sBuf + 260 * (t >> 1) + ((t & 1) << 7);  // member rows 8t..8t+7
    const float* ibase = mbase + 260 * 16;                        // item rows (+256)
    float logit[4] = {0.f, 0.f, 0.f, 0.f};
    #pragma unroll
    for (int fh = 0; fh < 2; ++fh) {
        float acc[4][8], pi[8];
        #pragma unroll
        for (int f = 0; f < 8; ++f) {
            pi[f] = 0.f;
            #pragma unroll
            for (int s = 0; s < 4; ++s) acc[s][f] = 0.f;
        }
        const float* mb = mbase + (fh << 3);
        const float* ib = ibase + (fh << 3);
        #pragma unroll
        for (int j = 0; j < 8; ++j) {
            float4 wa = *(const float4*)(mb + (j << 4));
            float4 wb = *(const float4*)(mb + (j << 4) + 4);
            float4 wc = *(const float4*)(ib + (j << 4));
            float4 wd = *(const float4*)(ib + (j << 4) + 4);
            #pragma unroll
            for (int s = 0; s < 4; ++s) {
                float mv = mbr[s][j];
                acc[s][0] += mv * wa.x; acc[s][1] += mv * wa.y;
                acc[s][2] += mv * wa.z; acc[s][3] += mv * wa.w;
                acc[s][4] += mv * wb.x; acc[s][5] += mv * wb.y;
                acc[s][6] += mv * wb.z; acc[s][7] += mv * wb.w;
            }
            float iv = itv[j];
            pi[0] += iv * wc.x; pi[1] += iv * wc.y; pi[2] += iv * wc.z; pi[3] += iv * wc.w;
            pi[4] += iv * wd.x; pi[5] += iv * wd.y; pi[6] += iv * wd.z; pi[7] += iv * wd.w;
        }
        float piR = rs8v(pi[0], pi[1], pi[2], pi[3], pi[4], pi[5], pi[6], pi[7],
                         b0, b1, b2);
        float hb  = piR + (fh ? ab1_1 : ab1_0);
        float w2v = fh ? aw2_1 : aw2_0;
        #pragma unroll
        for (int s = 0; s < 4; ++s) {
            float h = rs8v(acc[s][0], acc[s][1], acc[s][2], acc[s][3],
                           acc[s][4], acc[s][5], acc[s][6], acc[s][7],
                           b0, b1, b2) + hb;
            logit[s] += fmaxf(h, 0.f) * w2v;
        }
    }
    // octet all-reduce: each lane's partial is its feature's contribution
    #pragma unroll
    for (int s = 0; s < 4; ++s) {
        float v = logit[s];
        v += __shfl_xor(v, 1); v += __shfl_xor(v, 2); v += __shfl_xor(v, 4);
        logit[s] = v;
    }

    // ---- softmax over 4 members (b2 cancels) ----
    float l0 = logit[0], l1 = logit[1], l2 = logit[2], l3 = logit[3];
    float mx = fmaxf(fmaxf(l0, l1), fmaxf(l2, l3));
    float e0 = __expf(l0 - mx), e1 = __expf(l1 - mx);
    float e2 = __expf(l2 - mx), e3 = __expf(l3 - mx);
    float den = e0 + e1 + e2 + e3;
    float at0 = e0 / den, at1 = e1 / den, at2 = e2 / den, at3 = e3 / den;

    int best = 0; float bv = at0;
    if (at1 > bv) { bv = at1; best = 1; }
    if (at2 > bv) { bv = at2; best = 2; }
    if (at3 > bv) { bv = at3; best = 3; }
    int pc = (bv * cw1 + cb1) > (bv * cw0 + cb0) ? 1 : 0;

    // group embedding gather (latency hides under phase-B staging)
    float gvr[8];
    {
        const float4* p = (const float4*)group_emb + (((long)g) << 6) + (t << 1);
        float4 v0 = p[0], v1 = p[1];
        gvr[0] = v0.x; gvr[1] = v0.y; gvr[2] = v0.z; gvr[3] = v0.w;
        gvr[4] = v1.x; gvr[5] = v1.y; gvr[6] = v1.z; gvr[7] = v1.w;
    }

    // ---- phase B: stage pred_w1 (overwrites sBuf) ----
    __syncthreads();
    {
        const float4* srcp = (const float4*)pred_w1;     // 1536 float4
        for (int i = tid; i < 1536; i += 256) {
            float4 v = srcp[i];
            int r = i >> 1, cb = (i & 1) << 2;
            *(float4*)(sBuf + 132 * (r >> 4) + ((r & 15) << 3) + cb) = v;
        }
    }

    // g_att while staging is in flight
    float gvec[8], elv[8];
    #pragma unroll
    for (int d = 0; d < 8; ++d) {
        float w = at0 * mbr[0][d] + at1 * mbr[1][d] + at2 * mbr[2][d] + at3 * mbr[3][d];
        float ldr = mbr[0][d];
        ldr = (best == 1) ? mbr[1][d] : ldr;
        ldr = (best == 2) ? mbr[2][d] : ldr;
        ldr = (best == 3) ? mbr[3][d] : ldr;
        float ga = pc ? ldr : w;
        float gg = ga + gvr[d];
        gvec[d] = gg;
        elv[d]  = gg * itv[d];
    }
    __syncthreads();

    // ---- prediction MLP: [elem, g, items] (3*256) -> 8 -> 1 ----
    const float* pbase = sBuf + 132 * (t >> 1) + ((t & 1) << 6);
    float po[8] = {0.f,0.f,0.f,0.f,0.f,0.f,0.f,0.f};
    #pragma unroll
    for (int j = 0; j < 8; ++j) {
        const float* pA = pbase + (j << 3);
        float4 a0 = *(const float4*)pA,          a1 = *(const float4*)(pA + 4);
        float4 g0 = *(const float4*)(pA + 2112), g1 = *(const float4*)(pA + 2116);
        float4 c0 = *(const float4*)(pA + 4224), c1 = *(const float4*)(pA + 4228);
        float e = elv[j], gg = gvec[j], iv = itv[j];
        po[0] += e * a0.x; po[0] += gg * g0.x; po[0] += iv * c0.x;
        po[1] += e * a0.y; po[1] += gg * g0.y; po[1] += iv * c0.y;
        po[2] += e * a0.z; po[2] += gg * g0.z; po[2] += iv * c0.z;
        po[3] += e * a0.w; po[3] += gg * g0.w; po[3] += iv * c0.w;
        po[4] += e * a1.x; po[4] += gg * g1.x; po[4] += iv * c1.x;
        po[5] += e * a1.y; po[5] += gg * g1.y; po[5] += iv * c1.y;
        po[6] += e * a1.z; po[6] += gg * g1.z; po[6] += iv * c1.z;
        po[7] += e * a1.w; po[7] += gg * g1.w; po[7] += iv * c1.w;
    }
    float poR = rs8v(po[0], po[1], po[2], po[3], po[4], po[5], po[6], po[7],
                     b0, b1, b2);
    float z = fmaxf(poR + pb1v, 0.f) * pw2v;
    z += __shfl_xor(z, 1); z += __shfl_xor(z, 2); z += __shfl_xor(z, 4);
    z += pb2v;
    float y = 1.f / (1.f + __expf(-z));

    // ---- outputs: y[NB] | at_wt[NB*4] | pred_class[NB] ----
    if (t == 0) {
        out[b] = y;
        *(float4*)(out + NB + 4 * b) = make_float4(at0, at1, at2, at3);
        out[5 * NB + b] = (float)pc;
    }
}

extern "C" void kernel_launch(void* const* d_in, const int* in_sizes, int n_in,
                              void* d_out, int out_size, void* d_ws, size_t ws_size,
                              hipStream_t stream) {
    (void)in_sizes; (void)n_in; (void)out_size; (void)d_ws; (void)ws_size;
    agree_kernel<<<NB / GPB, 256, 0, stream>>>(
        (const int*)d_in[0], (const int*)d_in[1], (const int*)d_in[2],
        (const float*)d_in[3], (const float*)d_in[4], (const float*)d_in[5],
        (const float*)d_in[6], (const float*)d_in[7], (const float*)d_in[8],
        (const float*)d_in[9], (const float*)d_in[10], (const float*)d_in[11],
        (const float*)d_in[12], (const float*)d_in[13], (const float*)d_in[14],
        (const float*)d_in[15], (float*)d_out);
}

// Round 4
// 445.911 us; speedup vs baseline: 1.2924x; 1.1807x over previous
//
#include <hip/hip_runtime.h>

#define NB 65536     // groups per batch
#define GPB 8        // groups per block (256 threads, 32 lanes/group)

// Reduce-scatter an 8-vector over 32 lanes, all by value (no alloca).
// Returns full sum of feature f* = 4*b0+2*b1+b2 (bits of lane t).
__device__ __forceinline__ float rs8v(float v0, float v1, float v2, float v3,
                                      float v4, float v5, float v6, float v7,
                                      bool b0, bool b1, bool b2) {
    float s, r;
    s = b0 ? v0 : v4; r = __shfl_xor(s, 1); float w0 = (b0 ? v4 : v0) + r;
    s = b0 ? v1 : v5; r = __shfl_xor(s, 1); float w1 = (b0 ? v5 : v1) + r;
    s = b0 ? v2 : v6; r = __shfl_xor(s, 1); float w2 = (b0 ? v6 : v2) + r;
    s = b0 ? v3 : v7; r = __shfl_xor(s, 1); float w3 = (b0 ? v7 : v3) + r;
    s = b1 ? w0 : w2; r = __shfl_xor(s, 2); float x0 = (b1 ? w2 : w0) + r;
    s = b1 ? w1 : w3; r = __shfl_xor(s, 2); float x1 = (b1 ? w3 : w1) + r;
    s = b2 ? x0 : x1; r = __shfl_xor(s, 4); float u = (b2 ? x1 : x0) + r;
    u += __shfl_xor(u, 8);
    u += __shfl_xor(u, 16);
    return u;
}

// NOTE: no min-waves arg. __launch_bounds__(256, 4) made the allocator clamp
// to the 64-VGPR occupancy tier -> ~33 floats/thread spilled to scratch ->
// 590 MB of garbage HBM traffic (R2/R3 counters). Unconstrained allocation
// (R1) was spill-free at VGPR=144.
__global__ __launch_bounds__(256) void agree_kernel(
    const int* __restrict__ group_inputs,
    const int* __restrict__ item_inputs,
    const int* __restrict__ group_members,
    const float* __restrict__ user_emb,
    const float* __restrict__ item_emb,
    const float* __restrict__ group_emb,
    const float* __restrict__ att_w1,
    const float* __restrict__ att_b1,
    const float* __restrict__ att_w2,
    const float* __restrict__ att_b2,
    const float* __restrict__ cls_w,
    const float* __restrict__ cls_b,
    const float* __restrict__ pred_w1,
    const float* __restrict__ pred_b1,
    const float* __restrict__ pred_w2,
    const float* __restrict__ pred_b2,
    float* __restrict__ out)
{
    // Phase-split LDS union (33280 B -> 4 blocks/CU by LDS):
    //   phase A: att_w1 [512][16] as 32 chunks of 16 rows, chunk stride 260
    //   phase B: pred_w1 [768][8] as 48 chunks of 16 rows, chunk stride 132
    __shared__ __align__(16) float sBuf[32 * 260];

    const int tid = threadIdx.x;
    const int t = tid & 31;                 // lane within group (owns dims 8t..8t+7)
    const int b = blockIdx.x * GPB + (tid >> 5);

    // ---- issue gathers early (latency hides under weight staging) ----
    const int g  = group_inputs[b];
    const int it = item_inputs[b];
    const int4 mem = ((const int4*)group_members)[g];

    float mbr[4][8];
    {
        const int mi[4] = {mem.x, mem.y, mem.z, mem.w};
        #pragma unroll
        for (int s = 0; s < 4; ++s) {
            const float4* p = (const float4*)user_emb + (((long)mi[s]) << 6) + (t << 1);
            float4 v0 = p[0], v1 = p[1];
            mbr[s][0] = v0.x; mbr[s][1] = v0.y; mbr[s][2] = v0.z; mbr[s][3] = v0.w;
            mbr[s][4] = v1.x; mbr[s][5] = v1.y; mbr[s][6] = v1.z; mbr[s][7] = v1.w;
        }
    }
    float itv[8];
    {
        const float4* p = (const float4*)item_emb + (((long)it) << 6) + (t << 1);
        float4 v0 = p[0], v1 = p[1];
        itv[0] = v0.x; itv[1] = v0.y; itv[2] = v0.z; itv[3] = v0.w;
        itv[4] = v1.x; itv[5] = v1.y; itv[6] = v1.z; itv[7] = v1.w;
    }

    const bool b0 = (t & 1), b1 = (t & 2), b2 = (t & 4);
    // per-lane feature id for the reduce-scatter output
    const int fstar = ((t & 1) << 2) + (t & 2) + ((t >> 2) & 1);
    const float ab1_0 = att_b1[fstar],     ab1_1 = att_b1[8 + fstar];
    const float aw2_0 = att_w2[fstar],     aw2_1 = att_w2[8 + fstar];
    const float pb1v  = pred_b1[fstar],    pw2v  = pred_w2[fstar];
    const float pb2v  = pred_b2[0];
    const float cw0 = cls_w[0], cw1 = cls_w[1], cb0 = cls_b[0], cb1 = cls_b[1];

    // ---- phase A: stage att_w1 ----
    {
        const float4* src = (const float4*)att_w1;       // 2048 float4
        for (int i = tid; i < 2048; i += 256) {
            float4 v = src[i];
            int r = i >> 2, cb = (i & 3) << 2;
            *(float4*)(sBuf + 260 * (r >> 4) + ((r & 15) << 4) + cb) = v;
        }
    }
    __syncthreads();

    // ---- attention MLP: 2 passes of 8 hidden units ----
    const float* mbase = sBuf + 260 * (t >> 1) + ((t & 1) << 7);  // member rows 8t..8t+7
    const float* ibase = mbase + 260 * 16;                        // item rows (+256)
    float logit[4] = {0.f, 0.f, 0.f, 0.f};
    #pragma unroll
    for (int fh = 0; fh < 2; ++fh) {
        float acc[4][8], pi[8];
        #pragma unroll
        for (int f = 0; f < 8; ++f) {
            pi[f] = 0.f;
            #pragma unroll
            for (int s = 0; s < 4; ++s) acc[s][f] = 0.f;
        }
        const float* mb = mbase + (fh << 3);
        const float* ib = ibase + (fh << 3);
        #pragma unroll
        for (int j = 0; j < 8; ++j) {
            float4 wa = *(const float4*)(mb + (j << 4));
            float4 wb = *(const float4*)(mb + (j << 4) + 4);
            float4 wc = *(const float4*)(ib + (j << 4));
            float4 wd = *(const float4*)(ib + (j << 4) + 4);
            #pragma unroll
            for (int s = 0; s < 4; ++s) {
                float mv = mbr[s][j];
                acc[s][0] += mv * wa.x; acc[s][1] += mv * wa.y;
                acc[s][2] += mv * wa.z; acc[s][3] += mv * wa.w;
                acc[s][4] += mv * wb.x; acc[s][5] += mv * wb.y;
                acc[s][6] += mv * wb.z; acc[s][7] += mv * wb.w;
            }
            float iv = itv[j];
            pi[0] += iv * wc.x; pi[1] += iv * wc.y; pi[2] += iv * wc.z; pi[3] += iv * wc.w;
            pi[4] += iv * wd.x; pi[5] += iv * wd.y; pi[6] += iv * wd.z; pi[7] += iv * wd.w;
        }
        float piR = rs8v(pi[0], pi[1], pi[2], pi[3], pi[4], pi[5], pi[6], pi[7],
                         b0, b1, b2);
        float hb  = piR + (fh ? ab1_1 : ab1_0);
        float w2v = fh ? aw2_1 : aw2_0;
        #pragma unroll
        for (int s = 0; s < 4; ++s) {
            float h = rs8v(acc[s][0], acc[s][1], acc[s][2], acc[s][3],
                           acc[s][4], acc[s][5], acc[s][6], acc[s][7],
                           b0, b1, b2) + hb;
            logit[s] += fmaxf(h, 0.f) * w2v;
        }
    }
    // octet all-reduce: each lane's partial is its feature's contribution
    #pragma unroll
    for (int s = 0; s < 4; ++s) {
        float v = logit[s];
        v += __shfl_xor(v, 1); v += __shfl_xor(v, 2); v += __shfl_xor(v, 4);
        logit[s] = v;
    }

    // ---- softmax over 4 members (b2 cancels) ----
    float l0 = logit[0], l1 = logit[1], l2 = logit[2], l3 = logit[3];
    float mx = fmaxf(fmaxf(l0, l1), fmaxf(l2, l3));
    float e0 = __expf(l0 - mx), e1 = __expf(l1 - mx);
    float e2 = __expf(l2 - mx), e3 = __expf(l3 - mx);
    float den = e0 + e1 + e2 + e3;
    float at0 = e0 / den, at1 = e1 / den, at2 = e2 / den, at3 = e3 / den;

    int best = 0; float bv = at0;
    if (at1 > bv) { bv = at1; best = 1; }
    if (at2 > bv) { bv = at2; best = 2; }
    if (at3 > bv) { bv = at3; best = 3; }
    int pc = (bv * cw1 + cb1) > (bv * cw0 + cb0) ? 1 : 0;

    // group embedding gather (latency hides under phase-B staging)
    float gvr[8];
    {
        const float4* p = (const float4*)group_emb + (((long)g) << 6) + (t << 1);
        float4 v0 = p[0], v1 = p[1];
        gvr[0] = v0.x; gvr[1] = v0.y; gvr[2] = v0.z; gvr[3] = v0.w;
        gvr[4] = v1.x; gvr[5] = v1.y; gvr[6] = v1.z; gvr[7] = v1.w;
    }

    // ---- phase B: stage pred_w1 (overwrites sBuf) ----
    __syncthreads();
    {
        const float4* srcp = (const float4*)pred_w1;     // 1536 float4
        for (int i = tid; i < 1536; i += 256) {
            float4 v = srcp[i];
            int r = i >> 1, cb = (i & 1) << 2;
            *(float4*)(sBuf + 132 * (r >> 4) + ((r & 15) << 3) + cb) = v;
        }
    }

    // g_att while staging is in flight
    float gvec[8], elv[8];
    #pragma unroll
    for (int d = 0; d < 8; ++d) {
        float w = at0 * mbr[0][d] + at1 * mbr[1][d] + at2 * mbr[2][d] + at3 * mbr[3][d];
        float ldr = mbr[0][d];
        ldr = (best == 1) ? mbr[1][d] : ldr;
        ldr = (best == 2) ? mbr[2][d] : ldr;
        ldr = (best == 3) ? mbr[3][d] : ldr;
        float ga = pc ? ldr : w;
        float gg = ga + gvr[d];
        gvec[d] = gg;
        elv[d]  = gg * itv[d];
    }
    __syncthreads();

    // ---- prediction MLP: [elem, g, items] (3*256) -> 8 -> 1 ----
    const float* pbase = sBuf + 132 * (t >> 1) + ((t & 1) << 6);
    float po[8] = {0.f,0.f,0.f,0.f,0.f,0.f,0.f,0.f};
    #pragma unroll
    for (int j = 0; j < 8; ++j) {
        const float* pA = pbase + (j << 3);
        float4 a0 = *(const float4*)pA,          a1 = *(const float4*)(pA + 4);
        float4 g0 = *(const float4*)(pA + 2112), g1 = *(const float4*)(pA + 2116);
        float4 c0 = *(const float4*)(pA + 4224), c1 = *(const float4*)(pA + 4228);
        float e = elv[j], gg = gvec[j], iv = itv[j];
        po[0] += e * a0.x; po[0] += gg * g0.x; po[0] += iv * c0.x;
        po[1] += e * a0.y; po[1] += gg * g0.y; po[1] += iv * c0.y;
        po[2] += e * a0.z; po[2] += gg * g0.z; po[2] += iv * c0.z;
        po[3] += e * a0.w; po[3] += gg * g0.w; po[3] += iv * c0.w;
        po[4] += e * a1.x; po[4] += gg * g1.x; po[4] += iv * c1.x;
        po[5] += e * a1.y; po[5] += gg * g1.y; po[5] += iv * c1.y;
        po[6] += e * a1.z; po[6] += gg * g1.z; po[6] += iv * c1.z;
        po[7] += e * a1.w; po[7] += gg * g1.w; po[7] += iv * c1.w;
    }
    float poR = rs8v(po[0], po[1], po[2], po[3], po[4], po[5], po[6], po[7],
                     b0, b1, b2);
    float z = fmaxf(poR + pb1v, 0.f) * pw2v;
    z += __shfl_xor(z, 1); z += __shfl_xor(z, 2); z += __shfl_xor(z, 4);
    z += pb2v;
    float y = 1.f / (1.f + __expf(-z));

    // ---- outputs: y[NB] | at_wt[NB*4] | pred_class[NB] ----
    if (t == 0) {
        out[b] = y;
        *(float4*)(out + NB + 4 * b) = make_float4(at0, at1, at2, at3);
        out[5 * NB + b] = (float)pc;
    }
}

extern "C" void kernel_launch(void* const* d_in, const int* in_sizes, int n_in,
                              void* d_out, int out_size, void* d_ws, size_t ws_size,
                              hipStream_t stream) {
    (void)in_sizes; (void)n_in; (void)out_size; (void)d_ws; (void)ws_size;
    agree_kernel<<<NB / GPB, 256, 0, stream>>>(
        (const int*)d_in[0], (const int*)d_in[1], (const int*)d_in[2],
        (const float*)d_in[3], (const float*)d_in[4], (const float*)d_in[5],
        (const float*)d_in[6], (const float*)d_in[7], (const float*)d_in[8],
        (const float*)d_in[9], (const float*)d_in[10], (const float*)d_in[11],
        (const float*)d_in[12], (const float*)d_in[13], (const float*)d_in[14],
        (const float*)d_in[15], (float*)d_out);
}